// Round 12
// baseline (426.674 us; speedup 1.0000x reference)
//
#include <hip/hip_runtime.h>
#include <hip/hip_bf16.h>

#define NTHREADS 256
#define GB 256             // edge-pass blocks (histogram / scatter)
#define NB 256             // buckets (bucket = id >> 9; 196 used at N=100000)
#define BW 512             // nodes per bucket
#define CH 4864            // max edges per scatter block (E/GB = 4688)

typedef unsigned int uint32;
typedef unsigned long long u64;
typedef __bf16 bf16x8 __attribute__((ext_vector_type(8)));
typedef float f32x4 __attribute__((ext_vector_type(4)));

// ---------------- bf16 helpers ----------------

__device__ __forceinline__ float blo(uint32 u) { return __uint_as_float(u << 16); }
__device__ __forceinline__ float bhi(uint32 u) { return __uint_as_float(u & 0xffff0000u); }

__device__ __forceinline__ unsigned short bf16bits(float f) {
    __hip_bfloat16 h = __float2bfloat16(f);
    return *reinterpret_cast<unsigned short*>(&h);
}
__device__ __forceinline__ uint32 pk2(float a, float b) {
    return (uint32)bf16bits(a) | ((uint32)bf16bits(b) << 16);
}

// ---------------- K1: dual bucket histogram (LDS only, no global atomics) ----------------

__global__ __launch_bounds__(256) void histcols_k(const int* __restrict__ row,
                                                  const int* __restrict__ col,
                                                  int* __restrict__ bh, int* __restrict__ bh2,
                                                  int e, int ch) {
    __shared__ int h1[NB], h2[NB];
    int tid = threadIdx.x;
    h1[tid] = 0; h2[tid] = 0;
    __syncthreads();
    int beg = blockIdx.x * ch;
    int end = min(e, beg + ch);
    for (int i = beg + tid; i < end; i += 256) {
        atomicAdd(&h1[col[i] >> 9], 1);
        atomicAdd(&h2[row[i] >> 9], 1);
    }
    __syncthreads();
    bh[(size_t)tid * GB + blockIdx.x] = h1[tid];
    bh2[(size_t)tid * GB + blockIdx.x] = h2[tid];
}

// ---------------- K2: per-bucket exclusive scan over the GB blocks ----------------

__global__ __launch_bounds__(256) void scanb_k(int* bh, int* tb) {
    __shared__ int s[GB];
    int b = blockIdx.x;
    int tid = threadIdx.x;          // one block-slot per thread (GB == 256)
    size_t base = (size_t)b * GB + tid;
    int v = bh[base];
    s[tid] = v;
    __syncthreads();
    for (int off = 1; off < GB; off <<= 1) {
        int t = (tid >= off) ? s[tid - off] : 0;
        __syncthreads();
        s[tid] += t;
        __syncthreads();
    }
    bh[base] = s[tid] - v;          // exclusive
    if (tid == GB - 1) tb[b] = s[GB - 1];
}

// ---------------- K3: scan bucket totals -> global bucket bases ----------------

__global__ void scant_k(const int* __restrict__ tb, int* gbase) {
    __shared__ int s[256];
    int tid = threadIdx.x;
    int v = tb[tid];
    s[tid] = v;
    __syncthreads();
    for (int off = 1; off < 256; off <<= 1) {
        int t = (tid >= off) ? s[tid - off] : 0;
        __syncthreads();
        s[tid] += t;
        __syncthreads();
    }
    gbase[tid] = s[tid] - v;
    if (tid == 255) gbase[256] = s[255];
}

// ---------------- K4: LDS-sorted scatter (burst-coalesced writes) ----------------
// Each block locally bucket-sorts its edge chunk in LDS, then streams it out in
// sorted order so consecutive lanes write consecutive global slots (full lines
// assembled within one wave store burst -> no partial-line writeback churn).
// WRITECOL=1: key=col, writes st_col (9-bit id) + st_rw.  WRITECOL=0: key=row,
// writes st2 only.

template <int WRITECOL>
__global__ __launch_bounds__(256) void ldscat_k(const int* __restrict__ row,
                                                const int* __restrict__ col,
                                                const float* __restrict__ w,
                                                const int* __restrict__ bh,
                                                const int* __restrict__ gb,
                                                unsigned short* __restrict__ st_col,
                                                u64* __restrict__ st_rw,
                                                int e, int ch) {
    __shared__ u64 recs[CH];
    __shared__ uint32 cidx[CH];
    __shared__ int cnt[NB];
    __shared__ int base[NB];
    int tid = threadIdx.x, blk = blockIdx.x;
    cnt[tid] = 0;
    __syncthreads();
    int beg = blk * ch, end = min(e, beg + ch);
    const int* key = WRITECOL ? col : row;
    // pass 1: local histogram
    for (int i = beg + tid; i < end; i += 256)
        atomicAdd(&cnt[key[i] >> 9], 1);
    __syncthreads();
    // local exclusive scan
    int v = cnt[tid];
    base[tid] = v;
    __syncthreads();
    for (int off = 1; off < 256; off <<= 1) {
        int t = (tid >= off) ? base[tid - off] : 0;
        __syncthreads();
        base[tid] += t;
        __syncthreads();
    }
    int excl = base[tid] - v;
    __syncthreads();
    base[tid] = excl;
    cnt[tid] = excl;               // cursor
    __syncthreads();
    // pass 2: place into LDS bucket-sorted order
    for (int i = beg + tid; i < end; i += 256) {
        int k = key[i];
        int bk = k >> 9;
        int p = atomicAdd(&cnt[bk], 1);
        recs[p] = (u64)(uint32)row[i] | ((u64)__float_as_uint(w[i]) << 32);
        cidx[p] = (uint32)((bk << 9) | (k & (BW - 1)));
    }
    __syncthreads();
    // pass 3: burst write-out in sorted order
    int nblk = end - beg;
    for (int j = tid; j < nblk; j += 256) {
        uint32 ci = cidx[j];
        int bk = ci >> 9;
        int lrank = j - base[bk];
        int slot = gb[bk] + bh[(size_t)bk * GB + blk] + lrank;
        if (WRITECOL) st_col[slot] = (unsigned short)(ci & (BW - 1));
        st_rw[slot] = recs[j];
    }
}

// ---------------- K5: per-bucket degree accumulation (LDS fp32) -> dinv ----------------

__global__ __launch_bounds__(256) void bdeg_k(const u64* __restrict__ st2,
                                              const int* __restrict__ gb2,
                                              float* __restrict__ dinv, int n) {
    __shared__ float facc[BW];
    int bk = blockIdx.x;
    int tid = threadIdx.x;
    facc[tid] = 0.f; facc[tid + 256] = 0.f;
    __syncthreads();
    int beg = gb2[bk], end = gb2[bk + 1];
    for (int j = beg + tid; j < end; j += 256) {
        u64 v = st2[j];
        int r = (int)(uint32)v;
        float wv = __uint_as_float((uint32)(v >> 32));
        atomicAdd(&facc[r & (BW - 1)], wv);
    }
    __syncthreads();
    int n0 = bk * BW + tid, n1 = n0 + 256;
    if (n0 < n) dinv[n0] = rsqrtf(fmaxf(facc[tid] + 1.f, 1e-12f));
    if (n1 < n) dinv[n1] = rsqrtf(fmaxf(facc[tid + 256] + 1.f, 1e-12f));
}

// ---------------- K6: per-bucket node counts (LDS) ----------------

__global__ __launch_bounds__(256) void bcount_k(const unsigned short* __restrict__ st_col,
                                                const int* __restrict__ gb,
                                                int* __restrict__ counts, int n) {
    __shared__ int cnt[BW];
    int bk = blockIdx.x;
    int tid = threadIdx.x;
    cnt[tid] = 0; cnt[tid + 256] = 0;
    __syncthreads();
    int beg = gb[bk], end = gb[bk + 1];
    for (int j = beg + tid; j < end; j += 256)
        atomicAdd(&cnt[st_col[j]], 1);
    __syncthreads();
    int n0 = bk * BW + tid, n1 = n0 + 256;
    if (n0 < n) counts[n0] = cnt[tid];
    if (n1 < n) counts[n1] = cnt[tid + 256];
}

// ---------------- CSR offsets (scan over counts) ----------------

__global__ void scan1_k(const int* __restrict__ counts, int* offsets, int* blockSums, int n) {
    __shared__ int s[256];
    int tid = threadIdx.x;
    int idx = blockIdx.x * 256 + tid;
    int v = (idx < n) ? counts[idx] : 0;
    s[tid] = v;
    __syncthreads();
    for (int off = 1; off < 256; off <<= 1) {
        int t = (tid >= off) ? s[tid - off] : 0;
        __syncthreads();
        s[tid] += t;
        __syncthreads();
    }
    if (idx < n) offsets[idx] = s[tid] - v;
    if (tid == 255) blockSums[blockIdx.x] = s[255];
}

__global__ void scan2_k(int* blockSums, int nb) {
    __shared__ int s[1024];
    int tid = threadIdx.x;
    int v = (tid < nb) ? blockSums[tid] : 0;
    s[tid] = v;
    __syncthreads();
    for (int off = 1; off < 1024; off <<= 1) {
        int t = (tid >= off) ? s[tid - off] : 0;
        __syncthreads();
        s[tid] += t;
        __syncthreads();
    }
    if (tid < nb) blockSums[tid] = s[tid] - v;
}

__global__ void scan3_k(int* offsets, const int* __restrict__ blockSums, int n, int total) {
    int idx = blockIdx.x * blockDim.x + threadIdx.x;
    if (idx < n) offsets[idx] += blockSums[idx >> 8];
    if (idx == n) offsets[n] = total;
}

// ---------------- K7: per-bucket final CSR placement ----------------

__global__ __launch_bounds__(256) void bplace_k(const unsigned short* __restrict__ st_col,
                                                const u64* __restrict__ st_rw,
                                                const int* __restrict__ gb,
                                                const int* __restrict__ offsets,
                                                u64* __restrict__ csr) {
    __shared__ int cnt[BW];
    int bk = blockIdx.x;
    int tid = threadIdx.x;
    cnt[tid] = 0; cnt[tid + 256] = 0;
    __syncthreads();
    int beg = gb[bk], end = gb[bk + 1];
    for (int j = beg + tid; j < end; j += 256) {
        int c9 = st_col[j];
        int rank = atomicAdd(&cnt[c9], 1);
        int node = (bk << 9) | c9;
        csr[offsets[node] + rank] = st_rw[j];
    }
}

// ---------------- u-seed: ux = bf16(dinv * x) ----------------

__global__ void uxseed_k(const float* __restrict__ x, const float* __restrict__ dinv,
                         uint32* __restrict__ ux, int pairs) {
    int i = blockIdx.x * blockDim.x + threadIdx.x;
    if (i < pairs) {
        float di = dinv[i >> 5];          // 32 pairs per node
        float2 v = ((const float2*)x)[i];
        ux[i] = pk2(di * v.x, di * v.y);
    }
}

// ---------------- Horner in u-space: 4 nodes per wave, csr-prefetch pipeline ----------------

template <int MODE>
__global__ __launch_bounds__(256) void horner4n_k(
    const unsigned short* __restrict__ u_in,
    unsigned short* __restrict__ u_out,
    unsigned short* __restrict__ ybf,
    const unsigned short* __restrict__ ux_bf,
    const float* __restrict__ x,
    const float* __restrict__ dinv,
    const int* __restrict__ offsets,
    const u64* __restrict__ csr,
    int n)
{
    int wv = __builtin_amdgcn_readfirstlane(threadIdx.x >> 6);
    int lane = threadIdx.x & 63;
    int g = lane >> 3;   // group
    int s = lane & 7;    // 16B slice of a 128B bf16 row
    int nbase = blockIdx.x * 16 + wv * 4;

    int bb[4], ee[4];
#pragma unroll
    for (int m = 0; m < 4; ++m) {
        int node = nbase + m;
        if (node < n) { bb[m] = offsets[node]; ee[m] = offsets[node + 1]; }
        else          { bb[m] = 0; ee[m] = 0; }
    }
    int maxd = max(max(ee[0] - bb[0], ee[1] - bb[1]), max(ee[2] - bb[2], ee[3] - bb[3]));

    float acc[4][8];
#pragma unroll
    for (int m = 0; m < 4; ++m)
#pragma unroll
        for (int i = 0; i < 8; ++i) acc[m][i] = 0.f;

    u64 sw[4];
#pragma unroll
    for (int m = 0; m < 4; ++m) {
        int j = bb[m] + g;
        sw[m] = (j < ee[m]) ? csr[j] : 0ull;
    }

    for (int off = 0; off < maxd; off += 8) {
        uint4 q[4];
#pragma unroll
        for (int m = 0; m < 4; ++m)
            q[m] = ((const uint4*)(u_in + (size_t)(uint32)(sw[m] & 0xffffffffu) * 64))[s];
        u64 swn[4];
#pragma unroll
        for (int m = 0; m < 4; ++m) {
            int j = bb[m] + off + 8 + g;
            swn[m] = (j < ee[m]) ? csr[j] : 0ull;
        }
#pragma unroll
        for (int m = 0; m < 4; ++m) {
            float w = __uint_as_float((uint32)(sw[m] >> 32));
            acc[m][0] = fmaf(w, blo(q[m].x), acc[m][0]);
            acc[m][1] = fmaf(w, bhi(q[m].x), acc[m][1]);
            acc[m][2] = fmaf(w, blo(q[m].y), acc[m][2]);
            acc[m][3] = fmaf(w, bhi(q[m].y), acc[m][3]);
            acc[m][4] = fmaf(w, blo(q[m].z), acc[m][4]);
            acc[m][5] = fmaf(w, bhi(q[m].z), acc[m][5]);
            acc[m][6] = fmaf(w, blo(q[m].w), acc[m][6]);
            acc[m][7] = fmaf(w, bhi(q[m].w), acc[m][7]);
        }
#pragma unroll
        for (int m = 0; m < 4; ++m) sw[m] = swn[m];
    }

#pragma unroll
    for (int mask = 8; mask <= 32; mask <<= 1)
#pragma unroll
        for (int m = 0; m < 4; ++m)
#pragma unroll
            for (int i = 0; i < 8; ++i)
                acc[m][i] += __shfl_xor(acc[m][i], mask);

    float t[8];
#pragma unroll
    for (int i = 0; i < 8; ++i) {
        float a01 = (g == 0) ? acc[0][i] : acc[1][i];
        float a23 = (g == 2) ? acc[2][i] : acc[3][i];
        t[i] = (g < 2) ? a01 : a23;
    }

    if (g < 4) {
        int node = nbase + g;
        if (node < n) {
            float di = dinv[node];
            uint4 zq = ((const uint4*)(u_in + (size_t)node * 64))[s];  // self u-row slice
            t[0] += blo(zq.x); t[1] += bhi(zq.x);
            t[2] += blo(zq.y); t[3] += bhi(zq.y);
            t[4] += blo(zq.z); t[5] += bhi(zq.z);
            t[6] += blo(zq.w); t[7] += bhi(zq.w);
            if (MODE == 0) {
                float dd = di * di;
                uint4 xq = ((const uint4*)(ux_bf + (size_t)node * 64))[s];
                uint4 o;
                o.x = pk2(fmaf(dd, t[0], blo(xq.x)), fmaf(dd, t[1], bhi(xq.x)));
                o.y = pk2(fmaf(dd, t[2], blo(xq.y)), fmaf(dd, t[3], bhi(xq.y)));
                o.z = pk2(fmaf(dd, t[4], blo(xq.z)), fmaf(dd, t[5], bhi(xq.z)));
                o.w = pk2(fmaf(dd, t[6], blo(xq.w)), fmaf(dd, t[7], bhi(xq.w)));
                ((uint4*)(u_out + (size_t)node * 64))[s] = o;
            } else {
                float c = 0.09f * di;
                const float4* xr = (const float4*)(x + (size_t)node * 64);
                float4 xa = xr[s * 2], xb = xr[s * 2 + 1];
                uint4 o;
                o.x = pk2(fmaf(c, t[0], 0.1f * xa.x), fmaf(c, t[1], 0.1f * xa.y));
                o.y = pk2(fmaf(c, t[2], 0.1f * xa.z), fmaf(c, t[3], 0.1f * xa.w));
                o.z = pk2(fmaf(c, t[4], 0.1f * xb.x), fmaf(c, t[5], 0.1f * xb.y));
                o.w = pk2(fmaf(c, t[6], 0.1f * xb.z), fmaf(c, t[7], 0.1f * xb.w));
                ((uint4*)(ybf + (size_t)node * 64))[s] = o;
            }
        }
    }
}

// ---------------- MFMA MLP: relu(y@W0+b0)@W1+b1, bf16 inputs, fp32 accum ----------------

__global__ __launch_bounds__(256) void mlp_mfma_k(const unsigned short* __restrict__ ybf,
                                                  const float* __restrict__ W0,
                                                  const float* __restrict__ b0,
                                                  const float* __restrict__ W1,
                                                  const float* __restrict__ b1,
                                                  float* __restrict__ out, int n) {
    __shared__ __align__(16) unsigned short W0t[64 * 64];   // [j][k^swz]
    __shared__ __align__(16) unsigned short W1t[32 * 64];
    __shared__ __align__(16) unsigned short hidL[4][16 * 64]; // per-wave [node][h^swz]
    __shared__ float b0s[64], b1s[32];
    int tid = threadIdx.x;
    for (int i = tid; i < 64 * 64; i += 256) {
        int k = i >> 6, j = i & 63;
        W0t[j * 64 + (k ^ ((j & 7) << 3))] = bf16bits(W0[i]);
    }
    for (int i = tid; i < 64 * 32; i += 256) {
        int k = i >> 5, j = i & 31;
        W1t[j * 64 + (k ^ ((j & 7) << 3))] = bf16bits(W1[i]);
    }
    if (tid < 64) b0s[tid] = b0[tid];
    else if (tid < 96) b1s[tid - 64] = b1[tid - 64];
    __syncthreads();

    int wave = tid >> 6, lane = tid & 63;
    int r = lane & 15, g = lane >> 4;
    int nbase = blockIdx.x * 64 + wave * 16;

    int nodeA = min(nbase + r, n - 1);
    const bf16x8* yrow = (const bf16x8*)(ybf + (size_t)nodeA * 64);
    bf16x8 A0 = yrow[g];
    bf16x8 A1 = yrow[4 + g];

#pragma unroll
    for (int t = 0; t < 4; ++t) {
        int j = t * 16 + r;
        int sj = j & 7;
        const bf16x8* wcol = (const bf16x8*)(W0t + j * 64);
        bf16x8 B0 = wcol[g ^ sj];
        bf16x8 B1 = wcol[(4 + g) ^ sj];
        float bv = b0s[j];
        f32x4 acc = {bv, bv, bv, bv};
        acc = __builtin_amdgcn_mfma_f32_16x16x32_bf16(A0, B0, acc, 0, 0, 0);
        acc = __builtin_amdgcn_mfma_f32_16x16x32_bf16(A1, B1, acc, 0, 0, 0);
#pragma unroll
        for (int v = 0; v < 4; ++v) {
            int i = g * 4 + v;
            hidL[wave][i * 64 + (j ^ ((i & 7) << 3))] = bf16bits(fmaxf(acc[v], 0.f));
        }
    }

    const bf16x8* hrow = (const bf16x8*)(hidL[wave] + r * 64);
    int sr = r & 7;
    bf16x8 HA0 = hrow[g ^ sr];
    bf16x8 HA1 = hrow[(4 + g) ^ sr];
#pragma unroll
    for (int t = 0; t < 2; ++t) {
        int j = t * 16 + r;
        int sj = j & 7;
        const bf16x8* wcol = (const bf16x8*)(W1t + j * 64);
        bf16x8 B0 = wcol[g ^ sj];
        bf16x8 B1 = wcol[(4 + g) ^ sj];
        float bv = b1s[j];
        f32x4 acc = {bv, bv, bv, bv};
        acc = __builtin_amdgcn_mfma_f32_16x16x32_bf16(HA0, B0, acc, 0, 0, 0);
        acc = __builtin_amdgcn_mfma_f32_16x16x32_bf16(HA1, B1, acc, 0, 0, 0);
#pragma unroll
        for (int v = 0; v < 4; ++v) {
            int node = nbase + g * 4 + v;
            if (node < n) out[(size_t)node * 32 + j] = acc[v];
        }
    }
}

// ---------------- launch ----------------

extern "C" void kernel_launch(void* const* d_in, const int* in_sizes, int n_in,
                              void* d_out, int out_size, void* d_ws, size_t ws_size,
                              hipStream_t stream) {
    const float* x   = (const float*)d_in[0];
    const int*   ei  = (const int*)d_in[1];
    const float* ew  = (const float*)d_in[2];
    const float* W0  = (const float*)d_in[3];
    const float* b0  = (const float*)d_in[4];
    const float* W1  = (const float*)d_in[5];
    const float* b1  = (const float*)d_in[6];
    float* out = (float*)d_out;

    const int N = in_sizes[0] / 64;   // 100000
    const int E = in_sizes[2];        // 1200000
    const int* row = ei;
    const int* col = ei + E;

    char* p = (char*)d_ws;
    auto alloc = [&](size_t bytes) -> void* {
        void* r = (void*)p;
        p += (bytes + 255) & ~(size_t)255;
        return r;
    };
    float* dinv      = (float*)alloc((size_t)N * 4);
    int*   bh        = (int*)alloc((size_t)NB * GB * 4);
    int*   bh2       = (int*)alloc((size_t)NB * GB * 4);
    int*   tb        = (int*)alloc(NB * 4);
    int*   tb2       = (int*)alloc(NB * 4);
    int*   gb        = (int*)alloc((NB + 1) * 4);
    int*   gb2       = (int*)alloc((NB + 1) * 4);
    unsigned short* st_col = (unsigned short*)alloc((size_t)E * 2);
    u64*   st_rw     = (u64*)alloc((size_t)E * 8);
    int*   counts    = (int*)alloc((size_t)N * 4);
    int*   offsets   = (int*)alloc((size_t)(N + 1) * 4);
    int    nb        = (N + 255) / 256;
    int*   blockSums = (int*)alloc((size_t)nb * 4);
    u64*   csr       = (u64*)alloc((size_t)E * 8);   // doubles as st2 row-staging
    unsigned short* uxbf = (unsigned short*)alloc((size_t)N * 64 * 2);
    unsigned short* uA   = (unsigned short*)alloc((size_t)N * 64 * 2);
    unsigned short* uB   = (unsigned short*)alloc((size_t)N * 64 * 2);
    unsigned short* ybf  = (unsigned short*)alloc((size_t)N * 64 * 2);

    int ch = (E + GB - 1) / GB;   // 4688 <= CH

    histcols_k<<<GB, 256, 0, stream>>>(row, col, bh, bh2, E, ch);
    scanb_k<<<NB, 256, 0, stream>>>(bh, tb);
    scanb_k<<<NB, 256, 0, stream>>>(bh2, tb2);
    scant_k<<<1, 256, 0, stream>>>(tb, gb);
    scant_k<<<1, 256, 0, stream>>>(tb2, gb2);
    // LDS-sorted scatters: col-side (st_col+st_rw), row-side (st2 in csr buffer)
    ldscat_k<1><<<GB, 256, 0, stream>>>(row, col, ew, bh, gb, st_col, st_rw, E, ch);
    ldscat_k<0><<<GB, 256, 0, stream>>>(row, col, ew, bh2, gb2, nullptr, csr /*st2*/, E, ch);
    bdeg_k<<<NB, 256, 0, stream>>>(csr /*st2*/, gb2, dinv, N);
    bcount_k<<<NB, 256, 0, stream>>>(st_col, gb, counts, N);

    scan1_k<<<nb, 256, 0, stream>>>(counts, offsets, blockSums, N);
    scan2_k<<<1, 1024, 0, stream>>>(blockSums, nb);
    scan3_k<<<(N + 1 + NTHREADS - 1) / NTHREADS, NTHREADS, 0, stream>>>(offsets, blockSums, N, E);
    bplace_k<<<NB, 256, 0, stream>>>(st_col, st_rw, gb, offsets, csr);  // overwrites st2

    int pairs = N * 32;
    uxseed_k<<<(pairs + NTHREADS - 1) / NTHREADS, NTHREADS, 0, stream>>>(x, dinv,
                                                                         (uint32*)uxbf, pairs);

    // 9 Horner steps in u-space; first input is uxbf (= u0)
    int gP = (N + 15) / 16;
    const unsigned short* ui = uxbf;
    for (int k = 1; k <= 9; ++k) {
        unsigned short* uo = (ui == uA) ? uB : uA;
        horner4n_k<0><<<gP, 256, 0, stream>>>(ui, uo, nullptr, uxbf, x, dinv, offsets, csr, N);
        ui = uo;
    }
    // final: ybf = bf16(0.09*dinv*(W u_9) + 0.1*x)
    horner4n_k<1><<<gP, 256, 0, stream>>>(ui, nullptr, ybf, uxbf, x, dinv, offsets, csr, N);

    mlp_mfma_k<<<(N + 63) / 64, 256, 0, stream>>>(ybf, W0, b0, W1, b1, out, N);
}

// Round 13
// 414.531 us; speedup vs baseline: 1.0293x; 1.0293x over previous
//
#include <hip/hip_runtime.h>
#include <hip/hip_bf16.h>

#define NTHREADS 256
#define GB 256             // edge-pass blocks (histogram / replay)
#define NB 256             // buckets (bucket = id >> 9; 196 used at N=100000)
#define BW 512             // nodes per bucket

typedef unsigned int uint32;
typedef unsigned long long u64;
typedef __bf16 bf16x8 __attribute__((ext_vector_type(8)));
typedef float f32x4 __attribute__((ext_vector_type(4)));

// ---------------- bf16 helpers ----------------

__device__ __forceinline__ float blo(uint32 u) { return __uint_as_float(u << 16); }
__device__ __forceinline__ float bhi(uint32 u) { return __uint_as_float(u & 0xffff0000u); }

__device__ __forceinline__ unsigned short bf16bits(float f) {
    __hip_bfloat16 h = __float2bfloat16(f);
    return *reinterpret_cast<unsigned short*>(&h);
}
__device__ __forceinline__ uint32 pk2(float a, float b) {
    return (uint32)bf16bits(a) | ((uint32)bf16bits(b) << 16);
}

// ---------------- K1: dual bucket histogram (LDS only, no global atomics) ----------------

__global__ __launch_bounds__(256) void histcols_k(const int* __restrict__ row,
                                                  const int* __restrict__ col,
                                                  int* __restrict__ bh, int* __restrict__ bh2,
                                                  int e, int ch) {
    __shared__ int h1[NB], h2[NB];
    int tid = threadIdx.x;
    h1[tid] = 0; h2[tid] = 0;
    __syncthreads();
    int beg = blockIdx.x * ch;
    int end = min(e, beg + ch);
    for (int i = beg + tid; i < end; i += 256) {
        atomicAdd(&h1[col[i] >> 9], 1);
        atomicAdd(&h2[row[i] >> 9], 1);
    }
    __syncthreads();
    bh[(size_t)tid * GB + blockIdx.x] = h1[tid];
    bh2[(size_t)tid * GB + blockIdx.x] = h2[tid];
}

// ---------------- K2: per-bucket exclusive scan over the GB blocks ----------------

__global__ __launch_bounds__(256) void scanb_k(int* bh, int* tb) {
    __shared__ int s[GB];
    int b = blockIdx.x;
    int tid = threadIdx.x;          // one block-slot per thread (GB == 256)
    size_t base = (size_t)b * GB + tid;
    int v = bh[base];
    s[tid] = v;
    __syncthreads();
    for (int off = 1; off < GB; off <<= 1) {
        int t = (tid >= off) ? s[tid - off] : 0;
        __syncthreads();
        s[tid] += t;
        __syncthreads();
    }
    bh[base] = s[tid] - v;          // exclusive
    if (tid == GB - 1) tb[b] = s[GB - 1];
}

// ---------------- K3: scan bucket totals -> global bucket bases ----------------

__global__ void scant_k(const int* __restrict__ tb, int* gbase) {
    __shared__ int s[256];
    int tid = threadIdx.x;
    int v = tb[tid];
    s[tid] = v;
    __syncthreads();
    for (int off = 1; off < 256; off <<= 1) {
        int t = (tid >= off) ? s[tid - off] : 0;
        __syncthreads();
        s[tid] += t;
        __syncthreads();
    }
    gbase[tid] = s[tid] - v;
    if (tid == 255) gbase[256] = s[255];
}

// ---------------- K4: dual replay scatter into bucket-grouped staging ----------------
// st_col is u16: col & 511 (9 bits within bucket).

__global__ __launch_bounds__(256) void bscatter_k(const int* __restrict__ row,
                                                  const int* __restrict__ col,
                                                  const float* __restrict__ w,
                                                  const int* __restrict__ bh,
                                                  const int* __restrict__ bh2,
                                                  const int* __restrict__ gb,
                                                  const int* __restrict__ gb2,
                                                  unsigned short* __restrict__ st_col,
                                                  u64* __restrict__ st_rw,
                                                  u64* __restrict__ st2,
                                                  int e, int ch) {
    __shared__ int h1[NB], h2[NB];
    int tid = threadIdx.x;
    h1[tid] = 0; h2[tid] = 0;
    __syncthreads();
    int beg = blockIdx.x * ch;
    int end = min(e, beg + ch);
    for (int i = beg + tid; i < end; i += 256) {
        int c = col[i], r = row[i];
        float wv = w[i];
        u64 rec = (u64)(uint32)r | ((u64)__float_as_uint(wv) << 32);
        int bk = c >> 9;
        int rank = atomicAdd(&h1[bk], 1);
        int slot = gb[bk] + bh[(size_t)bk * GB + blockIdx.x] + rank;
        st_col[slot] = (unsigned short)(c & (BW - 1));
        st_rw[slot] = rec;
        int bk2 = r >> 9;
        int rank2 = atomicAdd(&h2[bk2], 1);
        int slot2 = gb2[bk2] + bh2[(size_t)bk2 * GB + blockIdx.x] + rank2;
        st2[slot2] = rec;
    }
}

// ---------------- K5: per-bucket degree accumulation (LDS fp32) -> dinv ----------------

__global__ __launch_bounds__(256) void bdeg_k(const u64* __restrict__ st2,
                                              const int* __restrict__ gb2,
                                              float* __restrict__ dinv, int n) {
    __shared__ float facc[BW];
    int bk = blockIdx.x;
    int tid = threadIdx.x;
    facc[tid] = 0.f; facc[tid + 256] = 0.f;
    __syncthreads();
    int beg = gb2[bk], end = gb2[bk + 1];
    for (int j = beg + tid; j < end; j += 256) {
        u64 v = st2[j];
        int r = (int)(uint32)v;
        float wv = __uint_as_float((uint32)(v >> 32));
        atomicAdd(&facc[r & (BW - 1)], wv);
    }
    __syncthreads();
    int n0 = bk * BW + tid, n1 = n0 + 256;
    if (n0 < n) dinv[n0] = rsqrtf(fmaxf(facc[tid] + 1.f, 1e-12f));
    if (n1 < n) dinv[n1] = rsqrtf(fmaxf(facc[tid + 256] + 1.f, 1e-12f));
}

// ---------------- K6: per-bucket node counts (LDS) ----------------

__global__ __launch_bounds__(256) void bcount_k(const unsigned short* __restrict__ st_col,
                                                const int* __restrict__ gb,
                                                int* __restrict__ counts, int n) {
    __shared__ int cnt[BW];
    int bk = blockIdx.x;
    int tid = threadIdx.x;
    cnt[tid] = 0; cnt[tid + 256] = 0;
    __syncthreads();
    int beg = gb[bk], end = gb[bk + 1];
    for (int j = beg + tid; j < end; j += 256)
        atomicAdd(&cnt[st_col[j]], 1);
    __syncthreads();
    int n0 = bk * BW + tid, n1 = n0 + 256;
    if (n0 < n) counts[n0] = cnt[tid];
    if (n1 < n) counts[n1] = cnt[tid + 256];
}

// ---------------- CSR offsets (scan over counts) ----------------

__global__ void scan1_k(const int* __restrict__ counts, int* offsets, int* blockSums, int n) {
    __shared__ int s[256];
    int tid = threadIdx.x;
    int idx = blockIdx.x * 256 + tid;
    int v = (idx < n) ? counts[idx] : 0;
    s[tid] = v;
    __syncthreads();
    for (int off = 1; off < 256; off <<= 1) {
        int t = (tid >= off) ? s[tid - off] : 0;
        __syncthreads();
        s[tid] += t;
        __syncthreads();
    }
    if (idx < n) offsets[idx] = s[tid] - v;
    if (tid == 255) blockSums[blockIdx.x] = s[255];
}

__global__ void scan2_k(int* blockSums, int nb) {
    __shared__ int s[1024];
    int tid = threadIdx.x;
    int v = (tid < nb) ? blockSums[tid] : 0;
    s[tid] = v;
    __syncthreads();
    for (int off = 1; off < 1024; off <<= 1) {
        int t = (tid >= off) ? s[tid - off] : 0;
        __syncthreads();
        s[tid] += t;
        __syncthreads();
    }
    if (tid < nb) blockSums[tid] = s[tid] - v;
}

__global__ void scan3_k(int* offsets, const int* __restrict__ blockSums, int n, int total) {
    int idx = blockIdx.x * blockDim.x + threadIdx.x;
    if (idx < n) offsets[idx] += blockSums[idx >> 8];
    if (idx == n) offsets[n] = total;
}

// ---------------- K7: per-bucket final CSR placement ----------------

__global__ __launch_bounds__(256) void bplace_k(const unsigned short* __restrict__ st_col,
                                                const u64* __restrict__ st_rw,
                                                const int* __restrict__ gb,
                                                const int* __restrict__ offsets,
                                                u64* __restrict__ csr) {
    __shared__ int cnt[BW];
    int bk = blockIdx.x;
    int tid = threadIdx.x;
    cnt[tid] = 0; cnt[tid + 256] = 0;
    __syncthreads();
    int beg = gb[bk], end = gb[bk + 1];
    for (int j = beg + tid; j < end; j += 256) {
        int c9 = st_col[j];
        int rank = atomicAdd(&cnt[c9], 1);
        int node = (bk << 9) | c9;
        csr[offsets[node] + rank] = st_rw[j];
    }
}

// ---------------- u-seed: ux = bf16(dinv * x) ----------------

__global__ void uxseed_k(const float* __restrict__ x, const float* __restrict__ dinv,
                         uint32* __restrict__ ux, int pairs) {
    int i = blockIdx.x * blockDim.x + threadIdx.x;
    if (i < pairs) {
        float di = dinv[i >> 5];          // 32 pairs per node
        float2 v = ((const float2*)x)[i];
        ux[i] = pk2(di * v.x, di * v.y);
    }
}

// ---------------- Horner in u-space: 4 nodes per wave, csr-prefetch pipeline ----------------

template <int MODE>
__global__ __launch_bounds__(256) void horner4n_k(
    const unsigned short* __restrict__ u_in,
    unsigned short* __restrict__ u_out,
    unsigned short* __restrict__ ybf,
    const unsigned short* __restrict__ ux_bf,
    const float* __restrict__ x,
    const float* __restrict__ dinv,
    const int* __restrict__ offsets,
    const u64* __restrict__ csr,
    int n)
{
    int wv = __builtin_amdgcn_readfirstlane(threadIdx.x >> 6);
    int lane = threadIdx.x & 63;
    int g = lane >> 3;   // group
    int s = lane & 7;    // 16B slice of a 128B bf16 row
    int nbase = blockIdx.x * 16 + wv * 4;

    int bb[4], ee[4];
#pragma unroll
    for (int m = 0; m < 4; ++m) {
        int node = nbase + m;
        if (node < n) { bb[m] = offsets[node]; ee[m] = offsets[node + 1]; }
        else          { bb[m] = 0; ee[m] = 0; }
    }
    int maxd = max(max(ee[0] - bb[0], ee[1] - bb[1]), max(ee[2] - bb[2], ee[3] - bb[3]));

    float acc[4][8];
#pragma unroll
    for (int m = 0; m < 4; ++m)
#pragma unroll
        for (int i = 0; i < 8; ++i) acc[m][i] = 0.f;

    u64 sw[4];
#pragma unroll
    for (int m = 0; m < 4; ++m) {
        int j = bb[m] + g;
        sw[m] = (j < ee[m]) ? csr[j] : 0ull;
    }

    for (int off = 0; off < maxd; off += 8) {
        uint4 q[4];
#pragma unroll
        for (int m = 0; m < 4; ++m)
            q[m] = ((const uint4*)(u_in + (size_t)(uint32)(sw[m] & 0xffffffffu) * 64))[s];
        u64 swn[4];
#pragma unroll
        for (int m = 0; m < 4; ++m) {
            int j = bb[m] + off + 8 + g;
            swn[m] = (j < ee[m]) ? csr[j] : 0ull;
        }
#pragma unroll
        for (int m = 0; m < 4; ++m) {
            float w = __uint_as_float((uint32)(sw[m] >> 32));
            acc[m][0] = fmaf(w, blo(q[m].x), acc[m][0]);
            acc[m][1] = fmaf(w, bhi(q[m].x), acc[m][1]);
            acc[m][2] = fmaf(w, blo(q[m].y), acc[m][2]);
            acc[m][3] = fmaf(w, bhi(q[m].y), acc[m][3]);
            acc[m][4] = fmaf(w, blo(q[m].z), acc[m][4]);
            acc[m][5] = fmaf(w, bhi(q[m].z), acc[m][5]);
            acc[m][6] = fmaf(w, blo(q[m].w), acc[m][6]);
            acc[m][7] = fmaf(w, bhi(q[m].w), acc[m][7]);
        }
#pragma unroll
        for (int m = 0; m < 4; ++m) sw[m] = swn[m];
    }

#pragma unroll
    for (int mask = 8; mask <= 32; mask <<= 1)
#pragma unroll
        for (int m = 0; m < 4; ++m)
#pragma unroll
            for (int i = 0; i < 8; ++i)
                acc[m][i] += __shfl_xor(acc[m][i], mask);

    float t[8];
#pragma unroll
    for (int i = 0; i < 8; ++i) {
        float a01 = (g == 0) ? acc[0][i] : acc[1][i];
        float a23 = (g == 2) ? acc[2][i] : acc[3][i];
        t[i] = (g < 2) ? a01 : a23;
    }

    if (g < 4) {
        int node = nbase + g;
        if (node < n) {
            float di = dinv[node];
            uint4 zq = ((const uint4*)(u_in + (size_t)node * 64))[s];  // self u-row slice
            t[0] += blo(zq.x); t[1] += bhi(zq.x);
            t[2] += blo(zq.y); t[3] += bhi(zq.y);
            t[4] += blo(zq.z); t[5] += bhi(zq.z);
            t[6] += blo(zq.w); t[7] += bhi(zq.w);
            if (MODE == 0) {
                float dd = di * di;
                uint4 xq = ((const uint4*)(ux_bf + (size_t)node * 64))[s];
                uint4 o;
                o.x = pk2(fmaf(dd, t[0], blo(xq.x)), fmaf(dd, t[1], bhi(xq.x)));
                o.y = pk2(fmaf(dd, t[2], blo(xq.y)), fmaf(dd, t[3], bhi(xq.y)));
                o.z = pk2(fmaf(dd, t[4], blo(xq.z)), fmaf(dd, t[5], bhi(xq.z)));
                o.w = pk2(fmaf(dd, t[6], blo(xq.w)), fmaf(dd, t[7], bhi(xq.w)));
                ((uint4*)(u_out + (size_t)node * 64))[s] = o;
            } else {
                float c = 0.09f * di;
                const float4* xr = (const float4*)(x + (size_t)node * 64);
                float4 xa = xr[s * 2], xb = xr[s * 2 + 1];
                uint4 o;
                o.x = pk2(fmaf(c, t[0], 0.1f * xa.x), fmaf(c, t[1], 0.1f * xa.y));
                o.y = pk2(fmaf(c, t[2], 0.1f * xa.z), fmaf(c, t[3], 0.1f * xa.w));
                o.z = pk2(fmaf(c, t[4], 0.1f * xb.x), fmaf(c, t[5], 0.1f * xb.y));
                o.w = pk2(fmaf(c, t[6], 0.1f * xb.z), fmaf(c, t[7], 0.1f * xb.w));
                ((uint4*)(ybf + (size_t)node * 64))[s] = o;
            }
        }
    }
}

// ---------------- MFMA MLP: relu(y@W0+b0)@W1+b1, bf16 inputs, fp32 accum ----------------

__global__ __launch_bounds__(256) void mlp_mfma_k(const unsigned short* __restrict__ ybf,
                                                  const float* __restrict__ W0,
                                                  const float* __restrict__ b0,
                                                  const float* __restrict__ W1,
                                                  const float* __restrict__ b1,
                                                  float* __restrict__ out, int n) {
    __shared__ __align__(16) unsigned short W0t[64 * 64];   // [j][k^swz]
    __shared__ __align__(16) unsigned short W1t[32 * 64];
    __shared__ __align__(16) unsigned short hidL[4][16 * 64]; // per-wave [node][h^swz]
    __shared__ float b0s[64], b1s[32];
    int tid = threadIdx.x;
    for (int i = tid; i < 64 * 64; i += 256) {
        int k = i >> 6, j = i & 63;
        W0t[j * 64 + (k ^ ((j & 7) << 3))] = bf16bits(W0[i]);
    }
    for (int i = tid; i < 64 * 32; i += 256) {
        int k = i >> 5, j = i & 31;
        W1t[j * 64 + (k ^ ((j & 7) << 3))] = bf16bits(W1[i]);
    }
    if (tid < 64) b0s[tid] = b0[tid];
    else if (tid < 96) b1s[tid - 64] = b1[tid - 64];
    __syncthreads();

    int wave = tid >> 6, lane = tid & 63;
    int r = lane & 15, g = lane >> 4;
    int nbase = blockIdx.x * 64 + wave * 16;

    int nodeA = min(nbase + r, n - 1);
    const bf16x8* yrow = (const bf16x8*)(ybf + (size_t)nodeA * 64);
    bf16x8 A0 = yrow[g];
    bf16x8 A1 = yrow[4 + g];

#pragma unroll
    for (int t = 0; t < 4; ++t) {
        int j = t * 16 + r;
        int sj = j & 7;
        const bf16x8* wcol = (const bf16x8*)(W0t + j * 64);
        bf16x8 B0 = wcol[g ^ sj];
        bf16x8 B1 = wcol[(4 + g) ^ sj];
        float bv = b0s[j];
        f32x4 acc = {bv, bv, bv, bv};
        acc = __builtin_amdgcn_mfma_f32_16x16x32_bf16(A0, B0, acc, 0, 0, 0);
        acc = __builtin_amdgcn_mfma_f32_16x16x32_bf16(A1, B1, acc, 0, 0, 0);
#pragma unroll
        for (int v = 0; v < 4; ++v) {
            int i = g * 4 + v;
            hidL[wave][i * 64 + (j ^ ((i & 7) << 3))] = bf16bits(fmaxf(acc[v], 0.f));
        }
    }

    const bf16x8* hrow = (const bf16x8*)(hidL[wave] + r * 64);
    int sr = r & 7;
    bf16x8 HA0 = hrow[g ^ sr];
    bf16x8 HA1 = hrow[(4 + g) ^ sr];
#pragma unroll
    for (int t = 0; t < 2; ++t) {
        int j = t * 16 + r;
        int sj = j & 7;
        const bf16x8* wcol = (const bf16x8*)(W1t + j * 64);
        bf16x8 B0 = wcol[g ^ sj];
        bf16x8 B1 = wcol[(4 + g) ^ sj];
        float bv = b1s[j];
        f32x4 acc = {bv, bv, bv, bv};
        acc = __builtin_amdgcn_mfma_f32_16x16x32_bf16(HA0, B0, acc, 0, 0, 0);
        acc = __builtin_amdgcn_mfma_f32_16x16x32_bf16(HA1, B1, acc, 0, 0, 0);
#pragma unroll
        for (int v = 0; v < 4; ++v) {
            int node = nbase + g * 4 + v;
            if (node < n) out[(size_t)node * 32 + j] = acc[v];
        }
    }
}

// ---------------- launch ----------------

extern "C" void kernel_launch(void* const* d_in, const int* in_sizes, int n_in,
                              void* d_out, int out_size, void* d_ws, size_t ws_size,
                              hipStream_t stream) {
    const float* x   = (const float*)d_in[0];
    const int*   ei  = (const int*)d_in[1];
    const float* ew  = (const float*)d_in[2];
    const float* W0  = (const float*)d_in[3];
    const float* b0  = (const float*)d_in[4];
    const float* W1  = (const float*)d_in[5];
    const float* b1  = (const float*)d_in[6];
    float* out = (float*)d_out;

    const int N = in_sizes[0] / 64;   // 100000
    const int E = in_sizes[2];        // 1200000
    const int* row = ei;
    const int* col = ei + E;

    char* p = (char*)d_ws;
    auto alloc = [&](size_t bytes) -> void* {
        void* r = (void*)p;
        p += (bytes + 255) & ~(size_t)255;
        return r;
    };
    float* dinv      = (float*)alloc((size_t)N * 4);
    int*   bh        = (int*)alloc((size_t)NB * GB * 4);
    int*   bh2       = (int*)alloc((size_t)NB * GB * 4);
    int*   tb        = (int*)alloc(NB * 4);
    int*   tb2       = (int*)alloc(NB * 4);
    int*   gb        = (int*)alloc((NB + 1) * 4);
    int*   gb2       = (int*)alloc((NB + 1) * 4);
    unsigned short* st_col = (unsigned short*)alloc((size_t)E * 2);
    u64*   st_rw     = (u64*)alloc((size_t)E * 8);
    int*   counts    = (int*)alloc((size_t)N * 4);
    int*   offsets   = (int*)alloc((size_t)(N + 1) * 4);
    int    nb        = (N + 255) / 256;
    int*   blockSums = (int*)alloc((size_t)nb * 4);
    u64*   csr       = (u64*)alloc((size_t)E * 8);   // doubles as st2 row-staging
    unsigned short* uxbf = (unsigned short*)alloc((size_t)N * 64 * 2);
    unsigned short* uA   = (unsigned short*)alloc((size_t)N * 64 * 2);
    unsigned short* uB   = (unsigned short*)alloc((size_t)N * 64 * 2);
    unsigned short* ybf  = (unsigned short*)alloc((size_t)N * 64 * 2);

    int ch = (E + GB - 1) / GB;

    histcols_k<<<GB, 256, 0, stream>>>(row, col, bh, bh2, E, ch);
    scanb_k<<<NB, 256, 0, stream>>>(bh, tb);
    scanb_k<<<NB, 256, 0, stream>>>(bh2, tb2);
    scant_k<<<1, 256, 0, stream>>>(tb, gb);
    scant_k<<<1, 256, 0, stream>>>(tb2, gb2);
    bscatter_k<<<GB, 256, 0, stream>>>(row, col, ew, bh, bh2, gb, gb2,
                                       st_col, st_rw, csr /*st2*/, E, ch);
    bdeg_k<<<NB, 256, 0, stream>>>(csr /*st2*/, gb2, dinv, N);
    bcount_k<<<NB, 256, 0, stream>>>(st_col, gb, counts, N);

    scan1_k<<<nb, 256, 0, stream>>>(counts, offsets, blockSums, N);
    scan2_k<<<1, 1024, 0, stream>>>(blockSums, nb);
    scan3_k<<<(N + 1 + NTHREADS - 1) / NTHREADS, NTHREADS, 0, stream>>>(offsets, blockSums, N, E);
    bplace_k<<<NB, 256, 0, stream>>>(st_col, st_rw, gb, offsets, csr);  // overwrites st2

    int pairs = N * 32;
    uxseed_k<<<(pairs + NTHREADS - 1) / NTHREADS, NTHREADS, 0, stream>>>(x, dinv,
                                                                         (uint32*)uxbf, pairs);

    // 9 Horner steps in u-space; first input is uxbf (= u0)
    int gP = (N + 15) / 16;
    const unsigned short* ui = uxbf;
    for (int k = 1; k <= 9; ++k) {
        unsigned short* uo = (ui == uA) ? uB : uA;
        horner4n_k<0><<<gP, 256, 0, stream>>>(ui, uo, nullptr, uxbf, x, dinv, offsets, csr, N);
        ui = uo;
    }
    // final: ybf = bf16(0.09*dinv*(W u_9) + 0.1*x)
    horner4n_k<1><<<gP, 256, 0, stream>>>(ui, nullptr, ybf, uxbf, x, dinv, offsets, csr, N);

    mlp_mfma_k<<<(N + 63) / 64, 256, 0, stream>>>(ybf, W0, b0, W1, b1, out, N);
}